// Round 7
// baseline (327.661 us; speedup 1.0000x reference)
//
#include <hip/hip_runtime.h>

#define Bz 32
#define Lz 1024
#define Hz 768
#define Sz 16

typedef float f32x4 __attribute__((ext_vector_type(4)));

// valid length of a monotone 1..10..0 amask row, computed wave-locally.
__device__ __forceinline__ int wave_valid(const int* __restrict__ amaskRow, int lane) {
  const int4* am4 = (const int4*)amaskRow;
  int s = 0;
#pragma unroll
  for (int j = 0; j < 4; ++j) {
    int4 a = am4[lane + j * 64];
    s += a.x + a.y + a.z + a.w;
  }
#pragma unroll
  for (int off = 32; off > 0; off >>= 1) s += __shfl_xor(s, off);
  return s;  // in all lanes
}

// ---------------- single fused kernel ----------------
// grid = Bz * 64 blocks, 256 threads (4 waves); each wave owns 4 rows,
// strided by 64 for load balance: q = local + (it*4 + wave) * 64.
// Row structure:
//   q >= v        : all zeros
//   q <  hist     : ones on [0, v)
//   hist <= q < v : ones on [0, hist) U [s0, s1)  where [s0,s1) is q's segment
// After mask+dot work, the last-finishing block of each batch reduces the
// per-position dots t[] into the 16 segment-mean logits (deterministic:
// one block, fixed order).
__global__ __launch_bounds__(256) void fused_all(
    const float* __restrict__ tokens, const int* __restrict__ amask,
    const int* __restrict__ bos, const float* __restrict__ fc_w,
    const float* __restrict__ fc_b, float* __restrict__ maskOut,
    float* __restrict__ logits, float* __restrict__ t, int* __restrict__ cnt) {
  int b = blockIdx.x >> 6;
  int local = blockIdx.x & 63;
  int wave = threadIdx.x >> 6;
  int lane = threadIdx.x & 63;

  int v = wave_valid(amask + b * Lz, lane);
  const int* bosRow = bos + b * Sz;
  int h = bosRow[0];

  // uniform weight fragments, hoisted (L1/L2-resident)
  const f32x4* wp = (const f32x4*)fc_w;
  f32x4 w0 = wp[lane];
  f32x4 w1 = wp[lane + 64];
  f32x4 w2 = wp[lane + 128];

#pragma unroll
  for (int it = 0; it < 4; ++it) {
    int q = local + ((it << 2) + wave) * 64;
    bool doDot = (q >= h && q < v);

    // issue token loads early so they overlap the mask store stream
    const f32x4* tp = (const f32x4*)(tokens + ((size_t)(b * Lz + q)) * Hz);
    f32x4 x0, x1, x2;
    if (doDot) {
      x0 = tp[lane];
      x1 = tp[lane + 64];
      x2 = tp[lane + 128];
    }

    int A, s0, s1;
    if (q >= v) { A = 0; s0 = 0; s1 = 0; }
    else if (q < h) { A = v; s0 = 0; s1 = 0; }
    else {
      int idx = -1;
#pragma unroll
      for (int s = 0; s < Sz; ++s) idx += (q >= bosRow[s]) ? 1 : 0;
      A = h;
      s0 = bosRow[idx];
      s1 = (idx < Sz - 1) ? bosRow[idx + 1] : v;
    }
    unsigned span = (unsigned)(s1 - s0);

    f32x4* row = (f32x4*)(maskOut + ((size_t)(b * Lz + q)) * Lz);
#pragma unroll
    for (int j = 0; j < 4; ++j) {
      int p0 = (lane + j * 64) * 4;
      f32x4 val;
      val.x = (p0 + 0 < A || (unsigned)(p0 + 0 - s0) < span) ? 1.f : 0.f;
      val.y = (p0 + 1 < A || (unsigned)(p0 + 1 - s0) < span) ? 1.f : 0.f;
      val.z = (p0 + 2 < A || (unsigned)(p0 + 2 - s0) < span) ? 1.f : 0.f;
      val.w = (p0 + 3 < A || (unsigned)(p0 + 3 - s0) < span) ? 1.f : 0.f;
      row[lane + j * 64] = val;
    }

    if (doDot) {
      float sum = x0.x * w0.x + x0.y * w0.y + x0.z * w0.z + x0.w * w0.w;
      sum += x1.x * w1.x + x1.y * w1.y + x1.z * w1.z + x1.w * w1.w;
      sum += x2.x * w2.x + x2.y * w2.y + x2.z * w2.z + x2.w * w2.w;
#pragma unroll
      for (int off = 32; off > 0; off >>= 1) sum += __shfl_down(sum, off);
      if (lane == 0) t[b * Lz + q] = sum;
    }
  }

  // ---- last block of this batch reduces t -> logits ----
  __shared__ int lastFlag;
  __threadfence();  // release this block's t stores to device scope
  __syncthreads();
  if (threadIdx.x == 0) {
    int old = atomicAdd(&cnt[b], 1);
    lastFlag = (old == 63) ? 1 : 0;
  }
  __syncthreads();
  if (lastFlag) {
    __threadfence();  // acquire: all 64 blocks' t stores visible
    float bias = fc_b[0];
#pragma unroll
    for (int ss = 0; ss < 4; ++ss) {
      int s = (wave << 2) + ss;  // 4 waves x 4 segments = 16
      int beg = bosRow[s];
      int end = (s < Sz - 1) ? bosRow[s + 1] : v;
      float sum = 0.f;
      for (int p = beg + lane; p < end; p += 64) sum += t[b * Lz + p];
#pragma unroll
      for (int off = 32; off > 0; off >>= 1) sum += __shfl_down(sum, off);
      if (lane == 0) logits[b * Sz + s] = sum / (float)(end - beg) + bias;
    }
  }
}

extern "C" void kernel_launch(void* const* d_in, const int* in_sizes, int n_in,
                              void* d_out, int out_size, void* d_ws, size_t ws_size,
                              hipStream_t stream) {
  const float* tokens = (const float*)d_in[0];
  const int* amask = (const int*)d_in[1];
  const int* bos = (const int*)d_in[2];
  const float* fc_w = (const float*)d_in[3];
  const float* fc_b = (const float*)d_in[4];

  float* out = (float*)d_out;
  float* logits = out;             // Bz*Sz floats
  float* maskOut = out + Bz * Sz;  // Bz*Lz*Lz floats (0/1)

  char* ws = (char*)d_ws;
  float* t = (float*)ws;                          // Bz*Lz floats
  int* cnt = (int*)(ws + (size_t)Bz * Lz * 4);    // Bz ints

  hipMemsetAsync(cnt, 0, Bz * sizeof(int), stream);
  fused_all<<<Bz * 64, 256, 0, stream>>>(tokens, amask, bos, fc_w, fc_b,
                                         maskOut, logits, t, cnt);
}

// Round 8
// 50.851 us; speedup vs baseline: 6.4435x; 6.4435x over previous
//
#include <hip/hip_runtime.h>

#define Bz 32
#define Lz 1024
#define Hz 768
#define Sz 16

typedef float f32x4 __attribute__((ext_vector_type(4)));

// valid length of a monotone 1..10..0 amask row, computed wave-locally.
__device__ __forceinline__ int wave_valid(const int* __restrict__ amaskRow, int lane) {
  const int4* am4 = (const int4*)amaskRow;
  int s = 0;
#pragma unroll
  for (int j = 0; j < 4; ++j) {
    int4 a = am4[lane + j * 64];
    s += a.x + a.y + a.z + a.w;
  }
#pragma unroll
  for (int off = 32; off > 0; off >>= 1) s += __shfl_xor(s, off);
  return s;  // in all lanes
}

// ---------------- single fused kernel (fence-free) ----------------
// grid = Bz * 64 blocks, 256 threads (4 waves); each wave owns 4 rows,
// strided by 64 for load balance: q = local + (it*4 + wave) * 64.
// Row structure:
//   q >= v        : all zeros
//   q <  hist     : ones on [0, v)
//   hist <= q < v : ones on [0, hist) U [s0, s1)  where [s0,s1) is q's segment
// Logits: logits[] is zeroed by a stream-ordered memset; each dot-row
// atomically adds dot/(segment length); block local==0 adds the bias.
// (float atomic ordering jitter ~1e-6, far below the 2e-2 check threshold)
__global__ __launch_bounds__(256) void fused_all(
    const float* __restrict__ tokens, const int* __restrict__ amask,
    const int* __restrict__ bos, const float* __restrict__ fc_w,
    const float* __restrict__ fc_b, float* __restrict__ maskOut,
    float* __restrict__ logits) {
  int b = blockIdx.x >> 6;
  int local = blockIdx.x & 63;
  int wave = threadIdx.x >> 6;
  int lane = threadIdx.x & 63;

  int v = wave_valid(amask + b * Lz, lane);
  const int* bosRow = bos + b * Sz;
  int h = bosRow[0];

  if (local == 0 && threadIdx.x < Sz) {
    atomicAdd(&logits[b * Sz + threadIdx.x], fc_b[0]);
  }

  // uniform weight fragments, hoisted (L1/L2-resident)
  const f32x4* wp = (const f32x4*)fc_w;
  f32x4 w0 = wp[lane];
  f32x4 w1 = wp[lane + 64];
  f32x4 w2 = wp[lane + 128];

#pragma unroll
  for (int it = 0; it < 4; ++it) {
    int q = local + ((it << 2) + wave) * 64;
    bool doDot = (q >= h && q < v);

    // issue token loads early so they overlap the mask store stream
    const f32x4* tp = (const f32x4*)(tokens + ((size_t)(b * Lz + q)) * Hz);
    f32x4 x0, x1, x2;
    if (doDot) {
      x0 = tp[lane];
      x1 = tp[lane + 64];
      x2 = tp[lane + 128];
    }

    int A, s0, s1, idx = 0;
    if (q >= v) { A = 0; s0 = 0; s1 = 0; }
    else if (q < h) { A = v; s0 = 0; s1 = 0; }
    else {
      idx = -1;
#pragma unroll
      for (int s = 0; s < Sz; ++s) idx += (q >= bosRow[s]) ? 1 : 0;
      A = h;
      s0 = bosRow[idx];
      s1 = (idx < Sz - 1) ? bosRow[idx + 1] : v;
    }
    unsigned span = (unsigned)(s1 - s0);

    f32x4* row = (f32x4*)(maskOut + ((size_t)(b * Lz + q)) * Lz);
#pragma unroll
    for (int j = 0; j < 4; ++j) {
      int p0 = (lane + j * 64) * 4;
      f32x4 val;
      val.x = (p0 + 0 < A || (unsigned)(p0 + 0 - s0) < span) ? 1.f : 0.f;
      val.y = (p0 + 1 < A || (unsigned)(p0 + 1 - s0) < span) ? 1.f : 0.f;
      val.z = (p0 + 2 < A || (unsigned)(p0 + 2 - s0) < span) ? 1.f : 0.f;
      val.w = (p0 + 3 < A || (unsigned)(p0 + 3 - s0) < span) ? 1.f : 0.f;
      row[lane + j * 64] = val;
    }

    if (doDot) {
      float sum = x0.x * w0.x + x0.y * w0.y + x0.z * w0.z + x0.w * w0.w;
      sum += x1.x * w1.x + x1.y * w1.y + x1.z * w1.z + x1.w * w1.w;
      sum += x2.x * w2.x + x2.y * w2.y + x2.z * w2.z + x2.w * w2.w;
#pragma unroll
      for (int off = 32; off > 0; off >>= 1) sum += __shfl_down(sum, off);
      if (lane == 0) atomicAdd(&logits[b * Sz + idx], sum / (float)span);
    }
  }
}

extern "C" void kernel_launch(void* const* d_in, const int* in_sizes, int n_in,
                              void* d_out, int out_size, void* d_ws, size_t ws_size,
                              hipStream_t stream) {
  const float* tokens = (const float*)d_in[0];
  const int* amask = (const int*)d_in[1];
  const int* bos = (const int*)d_in[2];
  const float* fc_w = (const float*)d_in[3];
  const float* fc_b = (const float*)d_in[4];

  float* out = (float*)d_out;
  float* logits = out;             // Bz*Sz floats
  float* maskOut = out + Bz * Sz;  // Bz*Lz*Lz floats (0/1)

  hipMemsetAsync(logits, 0, Bz * Sz * sizeof(float), stream);
  fused_all<<<Bz * 64, 256, 0, stream>>>(tokens, amask, bos, fc_w, fc_b,
                                         maskOut, logits);
}

// Round 9
// 31.680 us; speedup vs baseline: 10.3427x; 1.6051x over previous
//
#include <hip/hip_runtime.h>

#define Bz 32
#define Lz 1024
#define Hz 768
#define Sz 16

typedef float f32x4 __attribute__((ext_vector_type(4)));

// valid length of a monotone 1..10..0 amask row, computed wave-locally.
__device__ __forceinline__ int wave_valid(const int* __restrict__ amaskRow, int lane) {
  const int4* am4 = (const int4*)amaskRow;
  int s = 0;
#pragma unroll
  for (int j = 0; j < 4; ++j) {
    int4 a = am4[lane + j * 64];
    s += a.x + a.y + a.z + a.w;
  }
#pragma unroll
  for (int off = 32; off > 0; off >>= 1) s += __shfl_xor(s, off);
  return s;  // in all lanes
}

// ---------------- single kernel, two block roles ----------------
// blocks [0, Bz*Sz): logits blocks — block (b,s) computes the segment-mean
//   logit directly: dot each of the segment's token rows with fc_w, reduce.
//   Independent of mask blocks; deterministic (fixed order, no atomics).
// blocks [Bz*Sz, Bz*Sz + Bz*64): mask blocks — pure store streaming.
//   Each wave owns 4 rows strided by 64: q = local + (it*4 + wave) * 64.
//   Row structure:
//     q >= v        : all zeros
//     q <  hist     : ones on [0, v)
//     hist <= q < v : ones on [0, hist) U [s0, s1)  (q's segment)
__global__ __launch_bounds__(256) void fused_all(
    const float* __restrict__ tokens, const int* __restrict__ amask,
    const int* __restrict__ bos, const float* __restrict__ fc_w,
    const float* __restrict__ fc_b, float* __restrict__ maskOut,
    float* __restrict__ logits) {
  int bid = blockIdx.x;
  int wave = threadIdx.x >> 6;
  int lane = threadIdx.x & 63;

  if (bid < Bz * Sz) {
    // ---- logits block: one (b, s) segment ----
    int b = bid >> 4;
    int s = bid & (Sz - 1);
    int v = wave_valid(amask + b * Lz, lane);
    const int* bosRow = bos + b * Sz;
    int beg = bosRow[s];
    int end = (s < Sz - 1) ? bosRow[s + 1] : v;

    const f32x4* wp = (const f32x4*)fc_w;
    f32x4 w0 = wp[lane];
    f32x4 w1 = wp[lane + 64];
    f32x4 w2 = wp[lane + 128];

    float sum = 0.f;
    for (int p = beg + wave; p < end; p += 4) {
      const f32x4* tp = (const f32x4*)(tokens + ((size_t)(b * Lz + p)) * Hz);
      f32x4 x0 = tp[lane];
      f32x4 x1 = tp[lane + 64];
      f32x4 x2 = tp[lane + 128];
      sum += x0.x * w0.x + x0.y * w0.y + x0.z * w0.z + x0.w * w0.w;
      sum += x1.x * w1.x + x1.y * w1.y + x1.z * w1.z + x1.w * w1.w;
      sum += x2.x * w2.x + x2.y * w2.y + x2.z * w2.z + x2.w * w2.w;
    }
#pragma unroll
    for (int off = 32; off > 0; off >>= 1) sum += __shfl_down(sum, off);
    __shared__ float ws4[4];
    if (lane == 0) ws4[wave] = sum;
    __syncthreads();
    if (threadIdx.x == 0) {
      float tot = ws4[0] + ws4[1] + ws4[2] + ws4[3];
      logits[b * Sz + s] = tot / (float)(end - beg) + fc_b[0];
    }
  } else {
    // ---- mask block: 16 rows of batch b, pure stores ----
    int mbid = bid - Bz * Sz;
    int b = mbid >> 6;
    int local = mbid & 63;

    int v = wave_valid(amask + b * Lz, lane);
    const int* bosRow = bos + b * Sz;
    int h = bosRow[0];

#pragma unroll
    for (int it = 0; it < 4; ++it) {
      int q = local + ((it << 2) + wave) * 64;

      int A, s0, s1;
      if (q >= v) { A = 0; s0 = 0; s1 = 0; }
      else if (q < h) { A = v; s0 = 0; s1 = 0; }
      else {
        int idx = -1;
#pragma unroll
        for (int s = 0; s < Sz; ++s) idx += (q >= bosRow[s]) ? 1 : 0;
        A = h;
        s0 = bosRow[idx];
        s1 = (idx < Sz - 1) ? bosRow[idx + 1] : v;
      }
      unsigned span = (unsigned)(s1 - s0);

      f32x4* row = (f32x4*)(maskOut + ((size_t)(b * Lz + q)) * Lz);
#pragma unroll
      for (int j = 0; j < 4; ++j) {
        int p0 = (lane + j * 64) * 4;
        f32x4 val;
        val.x = (p0 + 0 < A || (unsigned)(p0 + 0 - s0) < span) ? 1.f : 0.f;
        val.y = (p0 + 1 < A || (unsigned)(p0 + 1 - s0) < span) ? 1.f : 0.f;
        val.z = (p0 + 2 < A || (unsigned)(p0 + 2 - s0) < span) ? 1.f : 0.f;
        val.w = (p0 + 3 < A || (unsigned)(p0 + 3 - s0) < span) ? 1.f : 0.f;
        row[lane + j * 64] = val;
      }
    }
  }
}

extern "C" void kernel_launch(void* const* d_in, const int* in_sizes, int n_in,
                              void* d_out, int out_size, void* d_ws, size_t ws_size,
                              hipStream_t stream) {
  const float* tokens = (const float*)d_in[0];
  const int* amask = (const int*)d_in[1];
  const int* bos = (const int*)d_in[2];
  const float* fc_w = (const float*)d_in[3];
  const float* fc_b = (const float*)d_in[4];

  float* out = (float*)d_out;
  float* logits = out;             // Bz*Sz floats
  float* maskOut = out + Bz * Sz;  // Bz*Lz*Lz floats (0/1)

  fused_all<<<Bz * Sz + Bz * 64, 256, 0, stream>>>(tokens, amask, bos, fc_w, fc_b,
                                                   maskOut, logits);
}